// Round 4
// baseline (2835.716 us; speedup 1.0000x reference)
//
#include <hip/hip_runtime.h>

#define DEVINL __device__ __forceinline__

constexpr int NT   = 32768;   // 64*512 nodes
constexpr int DH   = 128;
constexpr int NE   = 262144;
constexpr int BGR  = 64;
constexpr int NPG  = 512;
constexpr int LAYS = 5;
constexpr int ETILES = 4;     // edge tiles (128 edges each) per k_edge block

typedef __attribute__((ext_vector_type(8))) short bf16x8;
typedef __attribute__((ext_vector_type(4))) float f32x4;
typedef __attribute__((ext_vector_type(4))) unsigned int uint4v;
typedef unsigned int uint;

DEVINL float siluf(float v){ return v * (1.0f/(1.0f + __expf(-v))); }
DEVINL float tanh_fast(float x){ float e = __expf(2.0f*x); return 1.0f - 2.0f/(e + 1.0f); }

DEVINL uint bf16_rne(float f){
  uint x = __float_as_uint(f);
  return (x + 0x7fffu + ((x>>16)&1u)) >> 16;
}

// split one f32 into hi (truncated bf16) + lo (rne bf16 of residual): ~16-bit mantissa total
DEVINL void split8(const float* m, bf16x8& h, bf16x8& l){
  #pragma unroll
  for (int j=0;j<8;j++){
    uint x  = __float_as_uint(m[j]);
    uint hb = x >> 16;
    float hf = __uint_as_float(hb<<16);
    uint lb = bf16_rne(m[j] - hf);
    h[j] = (short)hb; l[j] = (short)lb;
  }
}

// 3-term split-bf16 MFMA accumulate: acc += A*B with ~f32 precision (drops al*bl)
DEVINL f32x4 mma3(bf16x8 ah, bf16x8 al, bf16x8 bh, bf16x8 bl, f32x4 acc){
  acc = __builtin_amdgcn_mfma_f32_16x16x32_bf16(al, bh, acc, 0,0,0);
  acc = __builtin_amdgcn_mfma_f32_16x16x32_bf16(ah, bl, acc, 0,0,0);
  acc = __builtin_amdgcn_mfma_f32_16x16x32_bf16(ah, bh, acc, 0,0,0);
  return acc;
}

// ---------------- weight prep: f32 [k][col] (or transposed) -> split bf16 planes laid out
// in MFMA B-fragment order: per 32-k chunk (8192 shorts): hi[q][col][8] at 0, lo at +4096.
// B-fragment (q,col) = shorts [kc*8192 + q*1024 + col*8 + j], j = k&7, q = (k&31)>>3 ----------------
template<int TRANS>
__global__ __launch_bounds__(256) void k_prep(const float* __restrict__ src, short* __restrict__ dst){
  const int idx = blockIdx.x*256 + threadIdx.x;
  const int k = idx>>7, col = idx&127;
  const float v = TRANS ? src[(size_t)col*128 + k] : src[(size_t)k*128 + col];
  uint hb = __float_as_uint(v) >> 16;
  float hf = __uint_as_float(hb<<16);
  uint lb = bf16_rne(v - hf);
  const int kc = k>>5, q = (k&31)>>3, j = k&7;
  const size_t o = (size_t)kc*8192 + q*1024 + col*8 + j;
  dst[o]        = (short)hb;
  dst[o + 4096] = (short)lb;
}

// ---------------- sort / degree ----------------
__global__ __launch_bounds__(256) void k_hist(const int* __restrict__ dst, int* __restrict__ cnt){
  int e = blockIdx.x*256 + threadIdx.x;
  atomicAdd(&cnt[dst[e]], 1);
}

__global__ __launch_bounds__(1024) void k_scan(const int* __restrict__ cnt, int* __restrict__ cur){
  __shared__ int part[1024];
  const int tid = threadIdx.x;
  const int base = tid*32;
  int s = 0;
  for (int i=0;i<32;i++) s += cnt[base+i];
  const int own = s;
  part[tid] = s; __syncthreads();
  for (int off=1; off<1024; off<<=1){
    int v = (tid>=off) ? part[tid-off] : 0;
    __syncthreads();
    part[tid] += v;
    __syncthreads();
  }
  int run = part[tid] - own;
  for (int i=0;i<32;i++){ cur[base+i] = run; run += cnt[base+i]; }
}

__global__ __launch_bounds__(256) void k_invdeg(const int* __restrict__ cnt, float* __restrict__ dinv){
  int n = blockIdx.x*256 + threadIdx.x;
  int c = cnt[n];
  dinv[n] = 1.0f / (float)(c > 1 ? c : 1);
}

__global__ __launch_bounds__(256) void k_scatter(const int* __restrict__ dst, int* __restrict__ cur,
                                                 int* __restrict__ perm){
  int e = blockIdx.x*256 + threadIdx.x;
  int p = atomicAdd(&cur[dst[e]], 1);
  perm[p] = e;
}

// ---------------- node-side MFMA GEMM: 128 rows/block, 8 waves ----------------
// MODE 0: embed  (A=feat, K=128, out h & h0)
// MODE 1: proj2  (A=h, K=128, two weight mats -> Aw(+be1), Bw)
// MODE 2: hupd1  (A=[h|aggm*dinv|h0], K=384, out c1 = silu(.+bh); zero-stores aggm)
// MODE 3: hupd2  (same, out h = silu(.+bh) - c1; zero-stores aggm)
template<int MODE>
__global__ __launch_bounds__(512) void k_ngemm(
    const float* __restrict__ A0, float* __restrict__ A1, const float* __restrict__ A2,
    const float* __restrict__ dinv, const short* __restrict__ W0, const short* __restrict__ W1,
    const float* __restrict__ bias, const float* __restrict__ c1in,
    float* __restrict__ out0, float* __restrict__ out1)
{
  __shared__ __align__(16) short wbuf[16384];   // 32 KB
  const int tid = threadIdx.x;
  const int wv = tid>>6, lane = tid&63, c = lane&15, q = lane>>4;
  const int row = blockIdx.x*128 + wv*16 + c;
  float dv = 1.0f;
  if constexpr (MODE>=2) dv = dinv[row];
  f32x4 accA[8], accB[8];
  #pragma unroll
  for (int t=0;t<8;t++){
    #pragma unroll
    for (int r=0;r<4;r++){ accA[t][r]=0.f; if constexpr (MODE==1) accB[t][r]=0.f; }
  }
  const int fo = q*1024 + c*8;    // fragment offset within chunk (+ t*128 per col tile)
  constexpr int NST = (MODE==1) ? 4 : ((MODE>=2) ? 6 : 2);
  for (int st=0; st<NST; ++st){
    __syncthreads();
    if constexpr (MODE==1){
      #pragma unroll
      for (int i=0;i<2;i++){
        ((uint4v*)wbuf)[tid + i*512]         = ((const uint4v*)(W0 + st*8192))[tid + i*512];
        ((uint4v*)(wbuf+8192))[tid + i*512]  = ((const uint4v*)(W1 + st*8192))[tid + i*512];
      }
    } else {
      #pragma unroll
      for (int i=0;i<4;i++)
        ((uint4v*)wbuf)[tid + i*512] = ((const uint4v*)(W0 + (size_t)st*16384))[tid + i*512];
    }
    __syncthreads();
    if constexpr (MODE==1){
      const int kb = st*32 + q*8;
      float4 v0 = *(const float4*)(A0 + (size_t)row*128 + kb);
      float4 v1 = *(const float4*)(A0 + (size_t)row*128 + kb + 4);
      float m[8] = {v0.x,v0.y,v0.z,v0.w,v1.x,v1.y,v1.z,v1.w};
      bf16x8 ah, al; split8(m, ah, al);
      #pragma unroll
      for (int t=0;t<8;t++){
        bf16x8 bhA = *(const bf16x8*)&wbuf[t*128 + fo];
        bf16x8 blA = *(const bf16x8*)&wbuf[4096 + t*128 + fo];
        bf16x8 bhB = *(const bf16x8*)&wbuf[8192 + t*128 + fo];
        bf16x8 blB = *(const bf16x8*)&wbuf[12288 + t*128 + fo];
        accA[t] = mma3(ah, al, bhA, blA, accA[t]);
        accB[t] = mma3(ah, al, bhB, blB, accB[t]);
      }
    } else {
      #pragma unroll
      for (int ks=0; ks<2; ++ks){
        const int kc = st*2 + ks;
        const float* asrc = A0; float sc = 1.0f; bool zero_a1 = false;
        if constexpr (MODE>=2){
          if (kc >= 8)      { asrc = A2; }
          else if (kc >= 4) { asrc = A1; sc = dv; zero_a1 = true; }
        }
        const int koff = (kc&3)*32 + q*8;
        float4 v0 = *(const float4*)(asrc + (size_t)row*128 + koff);
        float4 v1 = *(const float4*)(asrc + (size_t)row*128 + koff + 4);
        if constexpr (MODE>=2){
          if (zero_a1){   // consume-and-zero aggm (replaces next memset)
            float4 z; z.x=0.f; z.y=0.f; z.z=0.f; z.w=0.f;
            *(float4*)(A1 + (size_t)row*128 + koff)     = z;
            *(float4*)(A1 + (size_t)row*128 + koff + 4) = z;
          }
        }
        float m[8] = {v0.x*sc,v0.y*sc,v0.z*sc,v0.w*sc,v1.x*sc,v1.y*sc,v1.z*sc,v1.w*sc};
        bf16x8 ah, al; split8(m, ah, al);
        #pragma unroll
        for (int t=0;t<8;t++){
          bf16x8 bh = *(const bf16x8*)&wbuf[ks*8192 + t*128 + fo];
          bf16x8 bl = *(const bf16x8*)&wbuf[ks*8192 + 4096 + t*128 + fo];
          accA[t] = mma3(ah, al, bh, bl, accA[t]);
        }
      }
    }
  }
  // epilogue: C row = wv*16 + q*4 + r, col = t*16 + c
  #pragma unroll
  for (int t=0;t<8;t++){
    const int col = t*16 + c;
    float b0 = 0.f;
    if constexpr (MODE!=0) b0 = bias[col];
    #pragma unroll
    for (int r=0;r<4;r++){
      const size_t orow = (size_t)blockIdx.x*128 + wv*16 + q*4 + r;
      float v = accA[t][r];
      if constexpr (MODE==0){
        out0[orow*128 + col] = v; out1[orow*128 + col] = v;
      } else if constexpr (MODE==1){
        out0[orow*128 + col] = v + b0;
        out1[orow*128 + col] = accB[t][r];
      } else if constexpr (MODE==2){
        out0[orow*128 + col] = siluf(v + b0);
      } else {
        out0[orow*128 + col] = siluf(v + b0) - c1in[orow*128 + col];
      }
    }
  }
}

// ---------------- fused edge MLP (MFMA) + scatter ----------------
// Full We2 (both split planes, 64 KB) resident in LDS; each block sweeps ETILES tiles
// of 128 dst-sorted edges with NO barriers in the tile loop (per-wave LDS arrays only).
// Scatter uses a fully-static suffix-sum run compression (no runtime-indexed regs).
__global__ __launch_bounds__(512) void k_edge(
    const int* __restrict__ perm, const int* __restrict__ esrc, const int* __restrict__ edst,
    const float* __restrict__ x,  const float* __restrict__ Aw, const float* __restrict__ Bw,
    const short* __restrict__ w2p, const float* __restrict__ We1_l,
    const float* __restrict__ be2_l, const float* __restrict__ Wx_l,
    float* __restrict__ aggm, float* __restrict__ aggx)
{
  __shared__ __align__(16) short w2t[32768];   // 64 KB: full We2 (4 chunks x hi/lo)
  __shared__ __align__(16) float w256s[128];
  __shared__ __align__(16) float wxs[128];
  __shared__ __align__(16) float be2s[128];
  __shared__ float dxs[8][16][3];              // per-wave scratch (intra-wave only)
  __shared__ int   dsts[8][16];
  const int tid = threadIdx.x;
  const int wv = tid>>6, lane = tid&63, c = lane&15, q = lane>>4;
  if (tid < 128){ w256s[tid]=We1_l[256*128+tid]; wxs[tid]=Wx_l[tid]; be2s[tid]=be2_l[tid]; }
  #pragma unroll
  for (int i=0;i<8;i++)
    ((uint4v*)w2t)[tid + i*512] = ((const uint4v*)w2p)[tid + i*512];
  __syncthreads();   // the only block-wide barrier

  const int fo = q*1024 + c*8;
  for (int tile=0; tile<ETILES; ++tile){
    const int e0 = (blockIdx.x*ETILES + tile)*128;
    const int er = wv*16 + c;
    const int eg = perm[e0 + er];
    const int s  = esrc[eg], d = edst[eg];
    const float dx0 = x[s*3+0]-x[d*3+0];
    const float dx1 = x[s*3+1]-x[d*3+1];
    const float dx2 = x[s*3+2]-x[d*3+2];
    const float d2  = dx0*dx0 + dx1*dx1 + dx2*dx2;
    if (q==0){ dxs[wv][c][0]=dx0; dxs[wv][c][1]=dx1; dxs[wv][c][2]=dx2; dsts[wv][c]=d; }
    f32x4 acc[8];
    #pragma unroll
    for (int t=0;t<8;t++){ acc[t][0]=0.f; acc[t][1]=0.f; acc[t][2]=0.f; acc[t][3]=0.f; }
    const float* ap = Aw + (size_t)s*128;
    const float* bp = Bw + (size_t)d*128;
    #pragma unroll
    for (int kc=0; kc<4; ++kc){
      const int kb = kc*32 + q*8;
      float4 av0 = *(const float4*)(ap+kb), av1 = *(const float4*)(ap+kb+4);
      float4 bv0 = *(const float4*)(bp+kb), bv1 = *(const float4*)(bp+kb+4);
      float4 w0  = *(const float4*)&w256s[kb], w1 = *(const float4*)&w256s[kb+4];
      float m[8];
      m[0]=siluf(av0.x+bv0.x+d2*w0.x); m[1]=siluf(av0.y+bv0.y+d2*w0.y);
      m[2]=siluf(av0.z+bv0.z+d2*w0.z); m[3]=siluf(av0.w+bv0.w+d2*w0.w);
      m[4]=siluf(av1.x+bv1.x+d2*w1.x); m[5]=siluf(av1.y+bv1.y+d2*w1.y);
      m[6]=siluf(av1.z+bv1.z+d2*w1.z); m[7]=siluf(av1.w+bv1.w+d2*w1.w);
      bf16x8 ah, al; split8(m, ah, al);
      #pragma unroll
      for (int t=0;t<8;t++){
        bf16x8 bh = *(const bf16x8*)&w2t[kc*8192 + t*128 + fo];
        bf16x8 bl = *(const bf16x8*)&w2t[kc*8192 + 4096 + t*128 + fo];
        acc[t] = mma3(ah, al, bh, bl, acc[t]);
      }
    }
    // epilogue: edge row (in wave tile) = q*4 + r, col = t*16 + c
    float pd[4];
    #pragma unroll
    for (int t=0;t<8;t++){
      const float be = be2s[t*16+c], wx = wxs[t*16+c];
      #pragma unroll
      for (int r=0;r<4;r++){
        float v = siluf(acc[t][r] + be);
        acc[t][r] = v;
        if (t==0) pd[r] = v*wx; else pd[r] += v*wx;
      }
    }
    #pragma unroll
    for (int msk=1; msk<16; msk<<=1){
      #pragma unroll
      for (int r=0;r<4;r++) pd[r] += __shfl_xor(pd[r], msk);
    }
    const int rb = q*4;
    const int rd0 = dsts[wv][rb+0], rd1 = dsts[wv][rb+1];
    const int rd2 = dsts[wv][rb+2], rd3 = dsts[wv][rb+3];
    const bool b1 = (rd1!=rd0), b2 = (rd2!=rd1), b3 = (rd3!=rd2);
    { // agg_m scatter: static suffix-sum run compression
      #pragma unroll
      for (int t=0;t<8;t++){
        const int col = t*16 + c;
        float v3 = acc[t][3];
        float v2 = acc[t][2] + (b3 ? 0.f : v3);
        float v1 = acc[t][1] + (b2 ? 0.f : v2);
        float v0 = acc[t][0] + (b1 ? 0.f : v1);
        unsafeAtomicAdd(aggm + (size_t)rd0*128 + col, v0);
        if (b1) unsafeAtomicAdd(aggm + (size_t)rd1*128 + col, v1);
        if (b2) unsafeAtomicAdd(aggm + (size_t)rd2*128 + col, v2);
        if (b3) unsafeAtomicAdd(aggm + (size_t)rd3*128 + col, v3);
      }
    }
    if (c < 3){ // agg_x scatter, component c
      float a0 = dxs[wv][rb+0][c]*tanh_fast(pd[0]);
      float a1 = dxs[wv][rb+1][c]*tanh_fast(pd[1]);
      float a2 = dxs[wv][rb+2][c]*tanh_fast(pd[2]);
      float a3 = dxs[wv][rb+3][c]*tanh_fast(pd[3]);
      float v3 = a3;
      float v2 = a2 + (b3 ? 0.f : v3);
      float v1 = a1 + (b2 ? 0.f : v2);
      float v0 = a0 + (b1 ? 0.f : v1);
      unsafeAtomicAdd(aggx + (size_t)rd0*3 + c, v0);
      if (b1) unsafeAtomicAdd(aggx + (size_t)rd1*3 + c, v1);
      if (b2) unsafeAtomicAdd(aggx + (size_t)rd2*3 + c, v2);
      if (b3) unsafeAtomicAdd(aggx + (size_t)rd3*3 + c, v3);
    }
  }
}

// ---------------- coordinate update (consume-and-zero aggx) ----------------
__global__ __launch_bounds__(256) void k_xupd(float* __restrict__ x, const float* __restrict__ x0,
                                              float* __restrict__ aggx,
                                              const float* __restrict__ dinv){
  int i = blockIdx.x*256 + threadIdx.x;
  if (i < NT*3){
    int n = i/3;
    x[i] = 0.25f*x0[i] + 0.75f*x[i] + aggx[i]*dinv[n];
    aggx[i] = 0.f;
  }
}

// ---------------- masked mean pool (4-slice parallel) ----------------
__global__ __launch_bounds__(512) void k_pool(const float* __restrict__ h,
                                              const float* __restrict__ cvalid,
                                              float* __restrict__ pooled){
  __shared__ float red[4][128];
  __shared__ float redc[4];
  const int b = blockIdx.x, t = threadIdx.x, j = t&127, sl = t>>7;
  float s = 0.f, cf = 0.f;
  for (int n=sl; n<NPG; n+=4){
    const float m = cvalid[b*NPG + n];
    s  += h[((size_t)b*NPG + n)*DH + j] * m;
    cf += m;
  }
  red[sl][j] = s;
  if (j==0) redc[sl] = cf;
  __syncthreads();
  if (t < 128){
    float ss = red[0][t]+red[1][t]+red[2][t]+red[3][t];
    float cc = redc[0]+redc[1]+redc[2]+redc[3];
    pooled[b*DH + t] = ss / cc;
  }
}

// ---------------- final MLP head (single block) ----------------
__global__ __launch_bounds__(256) void k_mlp(const float* __restrict__ pooled,
                                             const float* __restrict__ Wfc,
                                             const float* __restrict__ bfc,
                                             const float* __restrict__ Wout,
                                             const float* __restrict__ bout,
                                             float* __restrict__ out)
{
  __shared__ __align__(16) float z[64*132];
  __shared__ __align__(16) float wB[128*128];
  const int t = threadIdx.x;
  {
    const int n = t>>2, qq = t&3;
    const float4* p = (const float4*)(pooled + n*DH + qq*32);
    float4* w = (float4*)&z[n*132 + qq*32];
    #pragma unroll
    for (int u=0;u<8;u++) w[u] = p[u];
  }
  const int g = t>>5, lane = t&31, c0 = lane*4;
  for (int l=0;l<3;l++){
    #pragma unroll
    for (int i=0;i<16;i++){
      const int idx = t + i*256;
      ((float4*)wB)[idx] = ((const float4*)(Wfc + (size_t)l*DH*DH))[idx];
    }
    __syncthreads();
    float acc[8][4];
    #pragma unroll
    for (int i=0;i<8;i++){ acc[i][0]=0.f; acc[i][1]=0.f; acc[i][2]=0.f; acc[i][3]=0.f; }
    #pragma unroll 4
    for (int kk=0; kk<128; kk+=4){
      float4 b0=*(const float4*)&wB[(kk+0)*128+c0];
      float4 b1=*(const float4*)&wB[(kk+1)*128+c0];
      float4 b2=*(const float4*)&wB[(kk+2)*128+c0];
      float4 b3=*(const float4*)&wB[(kk+3)*128+c0];
      #pragma unroll
      for (int i=0;i<8;i++){
        float4 a=*(const float4*)&z[(g*8+i)*132 + kk];
        acc[i][0]+=a.x*b0.x+a.y*b1.x+a.z*b2.x+a.w*b3.x;
        acc[i][1]+=a.x*b0.y+a.y*b1.y+a.z*b2.y+a.w*b3.y;
        acc[i][2]+=a.x*b0.z+a.y*b1.z+a.z*b2.z+a.w*b3.z;
        acc[i][3]+=a.x*b0.w+a.y*b1.w+a.z*b2.w+a.w*b3.w;
      }
    }
    __syncthreads();
    #pragma unroll
    for (int i=0;i<8;i++){
      float v0=acc[i][0]+bfc[l*DH+c0+0]; v0 = v0>0.f?v0:0.f;
      float v1=acc[i][1]+bfc[l*DH+c0+1]; v1 = v1>0.f?v1:0.f;
      float v2=acc[i][2]+bfc[l*DH+c0+2]; v2 = v2>0.f?v2:0.f;
      float v3=acc[i][3]+bfc[l*DH+c0+3]; v3 = v3>0.f?v3:0.f;
      float4 v; v.x=v0; v.y=v1; v.z=v2; v.w=v3;
      *(float4*)&z[(g*8+i)*132 + c0] = v;
    }
    __syncthreads();
  }
  if (t < 64){
    float a = 0.f;
    for (int k2=0;k2<128;k2++) a += z[t*132 + k2]*Wout[k2];
    out[t] = 1.0f/(1.0f + __expf(-(a + bout[0])));
  }
}

// ---------------- host ----------------
extern "C" void kernel_launch(void* const* d_in, const int* in_sizes, int n_in,
                              void* d_out, int out_size, void* d_ws, size_t ws_size,
                              hipStream_t stream)
{
  (void)in_sizes; (void)n_in; (void)out_size; (void)ws_size;
  const float* feat   = (const float*)d_in[0];
  const float* coords = (const float*)d_in[1];
  const float* cvalid = (const float*)d_in[2];
  const int*   esrc   = (const int*)d_in[3];
  const int*   edst   = (const int*)d_in[4];
  const int*   csrc   = (const int*)d_in[5];
  const int*   cdst   = (const int*)d_in[6];
  const float* W_emb  = (const float*)d_in[7];
  const float* We1    = (const float*)d_in[8];
  const float* be1    = (const float*)d_in[9];
  const float* We2    = (const float*)d_in[10];
  const float* be2    = (const float*)d_in[11];
  const float* Wx     = (const float*)d_in[12];
  const float* Wh     = (const float*)d_in[13];
  const float* bh     = (const float*)d_in[14];
  const float* Wfc    = (const float*)d_in[15];
  const float* bfc    = (const float*)d_in[16];
  const float* Wout   = (const float*)d_in[17];
  const float* bout   = (const float*)d_in[18];

  float* ws = (float*)d_ws;
  float* h      = ws; ws += (size_t)NT*DH;
  float* h0     = ws; ws += (size_t)NT*DH;
  float* c1     = ws; ws += (size_t)NT*DH;
  float* Aw     = ws; ws += (size_t)NT*DH;
  float* Bw     = ws; ws += (size_t)NT*DH;
  float* aggm   = ws; ws += (size_t)NT*DH;
  float* x      = ws; ws += (size_t)NT*3;
  float* aggx   = ws; ws += (size_t)NT*3;
  float* dgi    = ws; ws += NT;
  float* dci    = ws; ws += NT;
  float* pooled = ws; ws += BGR*DH;
  int* permG  = (int*)ws; ws += NE;
  int* permC  = (int*)ws; ws += NE;
  int* cnt    = (int*)ws; ws += NT;
  int* cursor = (int*)ws; ws += NT;
  // split-plane packed weight arena (bf16 shorts)
  short* pst    = (short*)ws;
  short* wemb_p = pst;                       // K=128 -> 4 chunks -> 32768 shorts
  const size_t LSTR = 32768*3 + 98304;       // we1a, we1b, we2 (32k each) + wh (98304)
  short* lay_p  = pst + 32768;

  // ---- zero accumulators once (consumers re-zero afterwards) ----
  hipMemsetAsync(aggm, 0, (size_t)NT*DH*sizeof(float), stream);
  hipMemsetAsync(aggx, 0, (size_t)NT*3*sizeof(float), stream);

  // ---- weight prep (tiny) ----
  k_prep<1><<<64, 256, 0, stream>>>(W_emb, wemb_p);
  for (int k=0;k<LAYS;k++){
    short* p = lay_p + (size_t)k*LSTR;
    k_prep<0><<<64,  256, 0, stream>>>(We1 + (size_t)k*257*DH,          p);
    k_prep<0><<<64,  256, 0, stream>>>(We1 + (size_t)k*257*DH + 128*DH, p + 32768);
    k_prep<0><<<64,  256, 0, stream>>>(We2 + (size_t)k*DH*DH,           p + 65536);
    k_prep<0><<<192, 256, 0, stream>>>(Wh  + (size_t)k*3*DH*DH,         p + 98304);
  }

  // ---- dst-sort both edge sets + degree inverses ----
  hipMemsetAsync(cnt, 0, NT*sizeof(int), stream);
  k_hist   <<<NE/256, 256, 0, stream>>>(edst, cnt);
  k_scan   <<<1, 1024, 0, stream>>>(cnt, cursor);
  k_invdeg <<<NT/256, 256, 0, stream>>>(cnt, dgi);
  k_scatter<<<NE/256, 256, 0, stream>>>(edst, cursor, permG);
  hipMemsetAsync(cnt, 0, NT*sizeof(int), stream);
  k_hist   <<<NE/256, 256, 0, stream>>>(cdst, cnt);
  k_scan   <<<1, 1024, 0, stream>>>(cnt, cursor);
  k_invdeg <<<NT/256, 256, 0, stream>>>(cnt, dci);
  k_scatter<<<NE/256, 256, 0, stream>>>(cdst, cursor, permC);

  // ---- embedding: h = feat @ W_emb^T ; h0 = h ; x = coords ----
  k_ngemm<0><<<NT/128, 512, 0, stream>>>(feat, nullptr, nullptr, nullptr,
                                         wemb_p, nullptr, nullptr, nullptr, h, h0);
  hipMemcpyAsync(x, coords, (size_t)NT*3*sizeof(float), hipMemcpyDeviceToDevice, stream);

  for (int k=0; k<LAYS; k++){
    short* p = lay_p + (size_t)k*LSTR;
    const float* We1_l = We1 + (size_t)k*257*DH;
    const float* be1_l = be1 + (size_t)k*DH;
    const float* be2_l = be2 + (size_t)k*DH;
    const float* Wx_l  = Wx  + (size_t)k*DH;
    const float* bh_l  = bh  + (size_t)k*DH;

    // node-side hoist of edge-MLP layer 1 (shared by graph & cross calls)
    k_ngemm<1><<<NT/128, 512, 0, stream>>>(h, nullptr, nullptr, nullptr,
                                           p, p + 32768, be1_l, nullptr, Aw, Bw);
    // --- graph edges ---
    k_edge<<<NE/(128*ETILES), 512, 0, stream>>>(permG, esrc, edst, x, Aw, Bw,
                                       p + 65536, We1_l, be2_l, Wx_l, aggm, aggx);
    k_xupd<<<(NT*3+255)/256, 256, 0, stream>>>(x, coords, aggx, dgi);
    k_ngemm<2><<<NT/128, 512, 0, stream>>>(h, aggm, h0, dgi,
                                           p + 98304, nullptr, bh_l, nullptr, c1, nullptr);
    // --- cross edges ---
    k_edge<<<NE/(128*ETILES), 512, 0, stream>>>(permC, csrc, cdst, x, Aw, Bw,
                                       p + 65536, We1_l, be2_l, Wx_l, aggm, aggx);
    k_xupd<<<(NT*3+255)/256, 256, 0, stream>>>(x, coords, aggx, dci);
    k_ngemm<3><<<NT/128, 512, 0, stream>>>(h, aggm, h0, dci,
                                           p + 98304, nullptr, bh_l, c1, h, nullptr);
  }

  k_pool<<<BGR, 512, 0, stream>>>(h, cvalid, pooled);
  k_mlp <<<1, 256, 0, stream>>>(pooled, Wfc, bfc, Wout, bout, (float*)d_out);
}

// Round 5
// 1694.120 us; speedup vs baseline: 1.6739x; 1.6739x over previous
//
#include <hip/hip_runtime.h>

#define DEVINL __device__ __forceinline__

constexpr int NT   = 32768;   // 64*512 nodes
constexpr int DH   = 128;
constexpr int NE   = 262144;
constexpr int BGR  = 64;
constexpr int NPG  = 512;
constexpr int LAYS = 5;

typedef __attribute__((ext_vector_type(8))) short bf16x8;
typedef __attribute__((ext_vector_type(4))) float f32x4;
typedef __attribute__((ext_vector_type(4))) unsigned int uint4v;
typedef unsigned int uint;

DEVINL float siluf(float v){ return v * (1.0f/(1.0f + __expf(-v))); }
DEVINL float tanh_fast(float x){ float e = __expf(2.0f*x); return 1.0f - 2.0f/(e + 1.0f); }

DEVINL uint bf16_rne(float f){
  uint x = __float_as_uint(f);
  return (x + 0x7fffu + ((x>>16)&1u)) >> 16;
}

// split one f32 into hi (truncated bf16) + lo (rne bf16 of residual): ~16-bit mantissa total
DEVINL void split8(const float* m, bf16x8& h, bf16x8& l){
  #pragma unroll
  for (int j=0;j<8;j++){
    uint x  = __float_as_uint(m[j]);
    uint hb = x >> 16;
    float hf = __uint_as_float(hb<<16);
    uint lb = bf16_rne(m[j] - hf);
    h[j] = (short)hb; l[j] = (short)lb;
  }
}

// 3-term split-bf16 MFMA accumulate: acc += A*B with ~f32 precision (drops al*bl)
DEVINL f32x4 mma3(bf16x8 ah, bf16x8 al, bf16x8 bh, bf16x8 bl, f32x4 acc){
  acc = __builtin_amdgcn_mfma_f32_16x16x32_bf16(al, bh, acc, 0,0,0);
  acc = __builtin_amdgcn_mfma_f32_16x16x32_bf16(ah, bl, acc, 0,0,0);
  acc = __builtin_amdgcn_mfma_f32_16x16x32_bf16(ah, bh, acc, 0,0,0);
  return acc;
}

// ---------------- weight prep: f32 [k][col] (or transposed) -> split bf16 planes laid out
// in MFMA B-fragment order: per 32-k chunk (8192 shorts): hi[q][col][8] at 0, lo at +4096.
// B-fragment (q,col) = shorts [kc*8192 + q*1024 + col*8 + j], j = k&7, q = (k&31)>>3 ----------------
template<int TRANS>
__global__ __launch_bounds__(256) void k_prep(const float* __restrict__ src, short* __restrict__ dst){
  const int idx = blockIdx.x*256 + threadIdx.x;
  const int k = idx>>7, col = idx&127;
  const float v = TRANS ? src[(size_t)col*128 + k] : src[(size_t)k*128 + col];
  uint hb = __float_as_uint(v) >> 16;
  float hf = __uint_as_float(hb<<16);
  uint lb = bf16_rne(v - hf);
  const int kc = k>>5, q = (k&31)>>3, j = k&7;
  const size_t o = (size_t)kc*8192 + q*1024 + col*8 + j;
  dst[o]        = (short)hb;
  dst[o + 4096] = (short)lb;
}

// ---------------- sort / degree ----------------
__global__ __launch_bounds__(256) void k_hist(const int* __restrict__ dst, int* __restrict__ cnt){
  int e = blockIdx.x*256 + threadIdx.x;
  atomicAdd(&cnt[dst[e]], 1);
}

__global__ __launch_bounds__(1024) void k_scan(const int* __restrict__ cnt, int* __restrict__ cur){
  __shared__ int part[1024];
  const int tid = threadIdx.x;
  const int base = tid*32;
  int s = 0;
  for (int i=0;i<32;i++) s += cnt[base+i];
  const int own = s;
  part[tid] = s; __syncthreads();
  for (int off=1; off<1024; off<<=1){
    int v = (tid>=off) ? part[tid-off] : 0;
    __syncthreads();
    part[tid] += v;
    __syncthreads();
  }
  int run = part[tid] - own;
  for (int i=0;i<32;i++){ cur[base+i] = run; run += cnt[base+i]; }
}

__global__ __launch_bounds__(256) void k_invdeg(const int* __restrict__ cnt, float* __restrict__ dinv){
  int n = blockIdx.x*256 + threadIdx.x;
  int c = cnt[n];
  dinv[n] = 1.0f / (float)(c > 1 ? c : 1);
}

__global__ __launch_bounds__(256) void k_scatter(const int* __restrict__ dst, int* __restrict__ cur,
                                                 int* __restrict__ perm){
  int e = blockIdx.x*256 + threadIdx.x;
  int p = atomicAdd(&cur[dst[e]], 1);
  perm[p] = e;
}

// ---------------- node-side MFMA GEMM: 128 rows/block, 8 waves ----------------
// MODE 0: embed  (A=feat, K=128, out h & h0)
// MODE 1: proj2  (A=h, K=128, two weight mats -> Aw(+be1), Bw)
// MODE 2: hupd1  (A=[h|aggm*dinv|h0], K=384, out c1 = silu(.+bh); zero-stores aggm)
// MODE 3: hupd2  (same, out h = silu(.+bh) - c1; zero-stores aggm)
template<int MODE>
__global__ __launch_bounds__(512) void k_ngemm(
    const float* __restrict__ A0, float* __restrict__ A1, const float* __restrict__ A2,
    const float* __restrict__ dinv, const short* __restrict__ W0, const short* __restrict__ W1,
    const float* __restrict__ bias, const float* __restrict__ c1in,
    float* __restrict__ out0, float* __restrict__ out1)
{
  __shared__ __align__(16) short wbuf[16384];   // 32 KB
  const int tid = threadIdx.x;
  const int wv = tid>>6, lane = tid&63, c = lane&15, q = lane>>4;
  const int row = blockIdx.x*128 + wv*16 + c;
  float dv = 1.0f;
  if constexpr (MODE>=2) dv = dinv[row];
  f32x4 accA[8], accB[8];
  #pragma unroll
  for (int t=0;t<8;t++){
    #pragma unroll
    for (int r=0;r<4;r++){ accA[t][r]=0.f; if constexpr (MODE==1) accB[t][r]=0.f; }
  }
  const int fo = q*1024 + c*8;    // fragment offset within chunk (+ t*128 per col tile)
  constexpr int NST = (MODE==1) ? 4 : ((MODE>=2) ? 6 : 2);
  for (int st=0; st<NST; ++st){
    __syncthreads();
    if constexpr (MODE==1){
      #pragma unroll
      for (int i=0;i<2;i++){
        ((uint4v*)wbuf)[tid + i*512]         = ((const uint4v*)(W0 + st*8192))[tid + i*512];
        ((uint4v*)(wbuf+8192))[tid + i*512]  = ((const uint4v*)(W1 + st*8192))[tid + i*512];
      }
    } else {
      #pragma unroll
      for (int i=0;i<4;i++)
        ((uint4v*)wbuf)[tid + i*512] = ((const uint4v*)(W0 + (size_t)st*16384))[tid + i*512];
    }
    __syncthreads();
    if constexpr (MODE==1){
      const int kb = st*32 + q*8;
      float4 v0 = *(const float4*)(A0 + (size_t)row*128 + kb);
      float4 v1 = *(const float4*)(A0 + (size_t)row*128 + kb + 4);
      float m[8] = {v0.x,v0.y,v0.z,v0.w,v1.x,v1.y,v1.z,v1.w};
      bf16x8 ah, al; split8(m, ah, al);
      #pragma unroll
      for (int t=0;t<8;t++){
        bf16x8 bhA = *(const bf16x8*)&wbuf[t*128 + fo];
        bf16x8 blA = *(const bf16x8*)&wbuf[4096 + t*128 + fo];
        bf16x8 bhB = *(const bf16x8*)&wbuf[8192 + t*128 + fo];
        bf16x8 blB = *(const bf16x8*)&wbuf[12288 + t*128 + fo];
        accA[t] = mma3(ah, al, bhA, blA, accA[t]);
        accB[t] = mma3(ah, al, bhB, blB, accB[t]);
      }
    } else {
      #pragma unroll
      for (int ks=0; ks<2; ++ks){
        const int kc = st*2 + ks;
        const float* asrc = A0; float sc = 1.0f; bool zero_a1 = false;
        if constexpr (MODE>=2){
          if (kc >= 8)      { asrc = A2; }
          else if (kc >= 4) { asrc = A1; sc = dv; zero_a1 = true; }
        }
        const int koff = (kc&3)*32 + q*8;
        float4 v0 = *(const float4*)(asrc + (size_t)row*128 + koff);
        float4 v1 = *(const float4*)(asrc + (size_t)row*128 + koff + 4);
        if constexpr (MODE>=2){
          if (zero_a1){   // consume-and-zero aggm (replaces next memset)
            float4 z; z.x=0.f; z.y=0.f; z.z=0.f; z.w=0.f;
            *(float4*)(A1 + (size_t)row*128 + koff)     = z;
            *(float4*)(A1 + (size_t)row*128 + koff + 4) = z;
          }
        }
        float m[8] = {v0.x*sc,v0.y*sc,v0.z*sc,v0.w*sc,v1.x*sc,v1.y*sc,v1.z*sc,v1.w*sc};
        bf16x8 ah, al; split8(m, ah, al);
        #pragma unroll
        for (int t=0;t<8;t++){
          bf16x8 bh = *(const bf16x8*)&wbuf[ks*8192 + t*128 + fo];
          bf16x8 bl = *(const bf16x8*)&wbuf[ks*8192 + 4096 + t*128 + fo];
          accA[t] = mma3(ah, al, bh, bl, accA[t]);
        }
      }
    }
  }
  // epilogue: C row = wv*16 + q*4 + r, col = t*16 + c
  #pragma unroll
  for (int t=0;t<8;t++){
    const int col = t*16 + c;
    float b0 = 0.f;
    if constexpr (MODE!=0) b0 = bias[col];
    #pragma unroll
    for (int r=0;r<4;r++){
      const size_t orow = (size_t)blockIdx.x*128 + wv*16 + q*4 + r;
      float v = accA[t][r];
      if constexpr (MODE==0){
        out0[orow*128 + col] = v; out1[orow*128 + col] = v;
      } else if constexpr (MODE==1){
        out0[orow*128 + col] = v + b0;
        out1[orow*128 + col] = accB[t][r];
      } else if constexpr (MODE==2){
        out0[orow*128 + col] = siluf(v + b0);
      } else {
        out0[orow*128 + col] = siluf(v + b0) - c1in[orow*128 + col];
      }
    }
  }
}

// ---------------- fused edge MLP (MFMA) + scatter: 128 dst-sorted edges per block ----------------
// R3 grid structure (one tile per block -> dispatcher-enforced moving window over the
// dst-sorted edge array = L2 locality for Aw/Bw gathers and aggm atomics) combined with
// R4's fully-static suffix-sum run compression (no runtime-indexed regs -> no scratch).
__global__ __launch_bounds__(512) void k_edge(
    const int* __restrict__ perm, const int* __restrict__ esrc, const int* __restrict__ edst,
    const float* __restrict__ x,  const float* __restrict__ Aw, const float* __restrict__ Bw,
    const short* __restrict__ w2p, const float* __restrict__ We1_l,
    const float* __restrict__ be2_l, const float* __restrict__ Wx_l,
    float* __restrict__ aggm, float* __restrict__ aggx)
{
  __shared__ __align__(16) short w2t[16384];   // 32 KB: 2 chunks (64 k) staged twice
  __shared__ __align__(16) float w256s[128];
  __shared__ __align__(16) float wxs[128];
  __shared__ __align__(16) float be2s[128];
  __shared__ float dxs[8][16][3];              // per-wave scratch (intra-wave only)
  __shared__ int   dsts[8][16];
  const int tid = threadIdx.x;
  const int wv = tid>>6, lane = tid&63, c = lane&15, q = lane>>4;
  if (tid < 128){ w256s[tid]=We1_l[256*128+tid]; wxs[tid]=Wx_l[tid]; be2s[tid]=be2_l[tid]; }
  const int er = wv*16 + c;
  const int eg = perm[blockIdx.x*128 + er];
  const int s  = esrc[eg], d = edst[eg];
  const float dx0 = x[s*3+0]-x[d*3+0];
  const float dx1 = x[s*3+1]-x[d*3+1];
  const float dx2 = x[s*3+2]-x[d*3+2];
  const float d2  = dx0*dx0 + dx1*dx1 + dx2*dx2;
  if (q==0){ dxs[wv][c][0]=dx0; dxs[wv][c][1]=dx1; dxs[wv][c][2]=dx2; dsts[wv][c]=d; }
  f32x4 acc[8];
  #pragma unroll
  for (int t=0;t<8;t++){ acc[t][0]=0.f; acc[t][1]=0.f; acc[t][2]=0.f; acc[t][3]=0.f; }
  const int fo = q*1024 + c*8;
  const float* ap = Aw + (size_t)s*128;
  const float* bp = Bw + (size_t)d*128;
  for (int half=0; half<2; ++half){
    __syncthreads();
    #pragma unroll
    for (int i=0;i<4;i++)
      ((uint4v*)w2t)[tid + i*512] = ((const uint4v*)(w2p + half*16384))[tid + i*512];
    __syncthreads();
    #pragma unroll
    for (int ks=0; ks<2; ++ks){
      const int kb = half*64 + ks*32 + q*8;
      float4 av0 = *(const float4*)(ap+kb), av1 = *(const float4*)(ap+kb+4);
      float4 bv0 = *(const float4*)(bp+kb), bv1 = *(const float4*)(bp+kb+4);
      float4 w0  = *(const float4*)&w256s[kb], w1 = *(const float4*)&w256s[kb+4];
      float m[8];
      m[0]=siluf(av0.x+bv0.x+d2*w0.x); m[1]=siluf(av0.y+bv0.y+d2*w0.y);
      m[2]=siluf(av0.z+bv0.z+d2*w0.z); m[3]=siluf(av0.w+bv0.w+d2*w0.w);
      m[4]=siluf(av1.x+bv1.x+d2*w1.x); m[5]=siluf(av1.y+bv1.y+d2*w1.y);
      m[6]=siluf(av1.z+bv1.z+d2*w1.z); m[7]=siluf(av1.w+bv1.w+d2*w1.w);
      bf16x8 ah, al; split8(m, ah, al);
      #pragma unroll
      for (int t=0;t<8;t++){
        bf16x8 bh = *(const bf16x8*)&w2t[ks*8192 + t*128 + fo];
        bf16x8 bl = *(const bf16x8*)&w2t[ks*8192 + 4096 + t*128 + fo];
        acc[t] = mma3(ah, al, bh, bl, acc[t]);
      }
    }
  }
  // epilogue: edge row (in wave tile) = q*4 + r, col = t*16 + c
  float pd[4];
  #pragma unroll
  for (int t=0;t<8;t++){
    const float be = be2s[t*16+c], wx = wxs[t*16+c];
    #pragma unroll
    for (int r=0;r<4;r++){
      float v = siluf(acc[t][r] + be);
      acc[t][r] = v;
      if (t==0) pd[r] = v*wx; else pd[r] += v*wx;
    }
  }
  #pragma unroll
  for (int msk=1; msk<16; msk<<=1){
    #pragma unroll
    for (int r=0;r<4;r++) pd[r] += __shfl_xor(pd[r], msk);
  }
  const int rb = q*4;
  const int rd0 = dsts[wv][rb+0], rd1 = dsts[wv][rb+1];
  const int rd2 = dsts[wv][rb+2], rd3 = dsts[wv][rb+3];
  const bool b1 = (rd1!=rd0), b2 = (rd2!=rd1), b3 = (rd3!=rd2);
  { // agg_m scatter: static suffix-sum run compression
    #pragma unroll
    for (int t=0;t<8;t++){
      const int col = t*16 + c;
      float v3 = acc[t][3];
      float v2 = acc[t][2] + (b3 ? 0.f : v3);
      float v1 = acc[t][1] + (b2 ? 0.f : v2);
      float v0 = acc[t][0] + (b1 ? 0.f : v1);
      unsafeAtomicAdd(aggm + (size_t)rd0*128 + col, v0);
      if (b1) unsafeAtomicAdd(aggm + (size_t)rd1*128 + col, v1);
      if (b2) unsafeAtomicAdd(aggm + (size_t)rd2*128 + col, v2);
      if (b3) unsafeAtomicAdd(aggm + (size_t)rd3*128 + col, v3);
    }
  }
  if (c < 3){ // agg_x scatter, component c
    float a0 = dxs[wv][rb+0][c]*tanh_fast(pd[0]);
    float a1 = dxs[wv][rb+1][c]*tanh_fast(pd[1]);
    float a2 = dxs[wv][rb+2][c]*tanh_fast(pd[2]);
    float a3 = dxs[wv][rb+3][c]*tanh_fast(pd[3]);
    float v3 = a3;
    float v2 = a2 + (b3 ? 0.f : v3);
    float v1 = a1 + (b2 ? 0.f : v2);
    float v0 = a0 + (b1 ? 0.f : v1);
    unsafeAtomicAdd(aggx + (size_t)rd0*3 + c, v0);
    if (b1) unsafeAtomicAdd(aggx + (size_t)rd1*3 + c, v1);
    if (b2) unsafeAtomicAdd(aggx + (size_t)rd2*3 + c, v2);
    if (b3) unsafeAtomicAdd(aggx + (size_t)rd3*3 + c, v3);
  }
}

// ---------------- coordinate update (consume-and-zero aggx) ----------------
__global__ __launch_bounds__(256) void k_xupd(float* __restrict__ x, const float* __restrict__ x0,
                                              float* __restrict__ aggx,
                                              const float* __restrict__ dinv){
  int i = blockIdx.x*256 + threadIdx.x;
  if (i < NT*3){
    int n = i/3;
    x[i] = 0.25f*x0[i] + 0.75f*x[i] + aggx[i]*dinv[n];
    aggx[i] = 0.f;
  }
}

// ---------------- masked mean pool (4-slice parallel) ----------------
__global__ __launch_bounds__(512) void k_pool(const float* __restrict__ h,
                                              const float* __restrict__ cvalid,
                                              float* __restrict__ pooled){
  __shared__ float red[4][128];
  __shared__ float redc[4];
  const int b = blockIdx.x, t = threadIdx.x, j = t&127, sl = t>>7;
  float s = 0.f, cf = 0.f;
  for (int n=sl; n<NPG; n+=4){
    const float m = cvalid[b*NPG + n];
    s  += h[((size_t)b*NPG + n)*DH + j] * m;
    cf += m;
  }
  red[sl][j] = s;
  if (j==0) redc[sl] = cf;
  __syncthreads();
  if (t < 128){
    float ss = red[0][t]+red[1][t]+red[2][t]+red[3][t];
    float cc = redc[0]+redc[1]+redc[2]+redc[3];
    pooled[b*DH + t] = ss / cc;
  }
}

// ---------------- final MLP head (single block) ----------------
__global__ __launch_bounds__(256) void k_mlp(const float* __restrict__ pooled,
                                             const float* __restrict__ Wfc,
                                             const float* __restrict__ bfc,
                                             const float* __restrict__ Wout,
                                             const float* __restrict__ bout,
                                             float* __restrict__ out)
{
  __shared__ __align__(16) float z[64*132];
  __shared__ __align__(16) float wB[128*128];
  const int t = threadIdx.x;
  {
    const int n = t>>2, qq = t&3;
    const float4* p = (const float4*)(pooled + n*DH + qq*32);
    float4* w = (float4*)&z[n*132 + qq*32];
    #pragma unroll
    for (int u=0;u<8;u++) w[u] = p[u];
  }
  const int g = t>>5, lane = t&31, c0 = lane*4;
  for (int l=0;l<3;l++){
    #pragma unroll
    for (int i=0;i<16;i++){
      const int idx = t + i*256;
      ((float4*)wB)[idx] = ((const float4*)(Wfc + (size_t)l*DH*DH))[idx];
    }
    __syncthreads();
    float acc[8][4];
    #pragma unroll
    for (int i=0;i<8;i++){ acc[i][0]=0.f; acc[i][1]=0.f; acc[i][2]=0.f; acc[i][3]=0.f; }
    #pragma unroll 4
    for (int kk=0; kk<128; kk+=4){
      float4 b0=*(const float4*)&wB[(kk+0)*128+c0];
      float4 b1=*(const float4*)&wB[(kk+1)*128+c0];
      float4 b2=*(const float4*)&wB[(kk+2)*128+c0];
      float4 b3=*(const float4*)&wB[(kk+3)*128+c0];
      #pragma unroll
      for (int i=0;i<8;i++){
        float4 a=*(const float4*)&z[(g*8+i)*132 + kk];
        acc[i][0]+=a.x*b0.x+a.y*b1.x+a.z*b2.x+a.w*b3.x;
        acc[i][1]+=a.x*b0.y+a.y*b1.y+a.z*b2.y+a.w*b3.y;
        acc[i][2]+=a.x*b0.z+a.y*b1.z+a.z*b2.z+a.w*b3.z;
        acc[i][3]+=a.x*b0.w+a.y*b1.w+a.z*b2.w+a.w*b3.w;
      }
    }
    __syncthreads();
    #pragma unroll
    for (int i=0;i<8;i++){
      float v0=acc[i][0]+bfc[l*DH+c0+0]; v0 = v0>0.f?v0:0.f;
      float v1=acc[i][1]+bfc[l*DH+c0+1]; v1 = v1>0.f?v1:0.f;
      float v2=acc[i][2]+bfc[l*DH+c0+2]; v2 = v2>0.f?v2:0.f;
      float v3=acc[i][3]+bfc[l*DH+c0+3]; v3 = v3>0.f?v3:0.f;
      float4 v; v.x=v0; v.y=v1; v.z=v2; v.w=v3;
      *(float4*)&z[(g*8+i)*132 + c0] = v;
    }
    __syncthreads();
  }
  if (t < 64){
    float a = 0.f;
    for (int k2=0;k2<128;k2++) a += z[t*132 + k2]*Wout[k2];
    out[t] = 1.0f/(1.0f + __expf(-(a + bout[0])));
  }
}

// ---------------- host ----------------
extern "C" void kernel_launch(void* const* d_in, const int* in_sizes, int n_in,
                              void* d_out, int out_size, void* d_ws, size_t ws_size,
                              hipStream_t stream)
{
  (void)in_sizes; (void)n_in; (void)out_size; (void)ws_size;
  const float* feat   = (const float*)d_in[0];
  const float* coords = (const float*)d_in[1];
  const float* cvalid = (const float*)d_in[2];
  const int*   esrc   = (const int*)d_in[3];
  const int*   edst   = (const int*)d_in[4];
  const int*   csrc   = (const int*)d_in[5];
  const int*   cdst   = (const int*)d_in[6];
  const float* W_emb  = (const float*)d_in[7];
  const float* We1    = (const float*)d_in[8];
  const float* be1    = (const float*)d_in[9];
  const float* We2    = (const float*)d_in[10];
  const float* be2    = (const float*)d_in[11];
  const float* Wx     = (const float*)d_in[12];
  const float* Wh     = (const float*)d_in[13];
  const float* bh     = (const float*)d_in[14];
  const float* Wfc    = (const float*)d_in[15];
  const float* bfc    = (const float*)d_in[16];
  const float* Wout   = (const float*)d_in[17];
  const float* bout   = (const float*)d_in[18];

  float* ws = (float*)d_ws;
  float* h      = ws; ws += (size_t)NT*DH;
  float* h0     = ws; ws += (size_t)NT*DH;
  float* c1     = ws; ws += (size_t)NT*DH;
  float* Aw     = ws; ws += (size_t)NT*DH;
  float* Bw     = ws; ws += (size_t)NT*DH;
  float* aggm   = ws; ws += (size_t)NT*DH;
  float* x      = ws; ws += (size_t)NT*3;
  float* aggx   = ws; ws += (size_t)NT*3;
  float* dgi    = ws; ws += NT;
  float* dci    = ws; ws += NT;
  float* pooled = ws; ws += BGR*DH;
  int* permG  = (int*)ws; ws += NE;
  int* permC  = (int*)ws; ws += NE;
  int* cnt    = (int*)ws; ws += NT;
  int* cursor = (int*)ws; ws += NT;
  // split-plane packed weight arena (bf16 shorts)
  short* pst    = (short*)ws;
  short* wemb_p = pst;                       // K=128 -> 4 chunks -> 32768 shorts
  const size_t LSTR = 32768*3 + 98304;       // we1a, we1b, we2 (32k each) + wh (98304)
  short* lay_p  = pst + 32768;

  // ---- zero accumulators once (consumers re-zero afterwards) ----
  hipMemsetAsync(aggm, 0, (size_t)NT*DH*sizeof(float), stream);
  hipMemsetAsync(aggx, 0, (size_t)NT*3*sizeof(float), stream);

  // ---- weight prep (tiny) ----
  k_prep<1><<<64, 256, 0, stream>>>(W_emb, wemb_p);
  for (int k=0;k<LAYS;k++){
    short* p = lay_p + (size_t)k*LSTR;
    k_prep<0><<<64,  256, 0, stream>>>(We1 + (size_t)k*257*DH,          p);
    k_prep<0><<<64,  256, 0, stream>>>(We1 + (size_t)k*257*DH + 128*DH, p + 32768);
    k_prep<0><<<64,  256, 0, stream>>>(We2 + (size_t)k*DH*DH,           p + 65536);
    k_prep<0><<<192, 256, 0, stream>>>(Wh  + (size_t)k*3*DH*DH,         p + 98304);
  }

  // ---- dst-sort both edge sets + degree inverses ----
  hipMemsetAsync(cnt, 0, NT*sizeof(int), stream);
  k_hist   <<<NE/256, 256, 0, stream>>>(edst, cnt);
  k_scan   <<<1, 1024, 0, stream>>>(cnt, cursor);
  k_invdeg <<<NT/256, 256, 0, stream>>>(cnt, dgi);
  k_scatter<<<NE/256, 256, 0, stream>>>(edst, cursor, permG);
  hipMemsetAsync(cnt, 0, NT*sizeof(int), stream);
  k_hist   <<<NE/256, 256, 0, stream>>>(cdst, cnt);
  k_scan   <<<1, 1024, 0, stream>>>(cnt, cursor);
  k_invdeg <<<NT/256, 256, 0, stream>>>(cnt, dci);
  k_scatter<<<NE/256, 256, 0, stream>>>(cdst, cursor, permC);

  // ---- embedding: h = feat @ W_emb^T ; h0 = h ; x = coords ----
  k_ngemm<0><<<NT/128, 512, 0, stream>>>(feat, nullptr, nullptr, nullptr,
                                         wemb_p, nullptr, nullptr, nullptr, h, h0);
  hipMemcpyAsync(x, coords, (size_t)NT*3*sizeof(float), hipMemcpyDeviceToDevice, stream);

  for (int k=0; k<LAYS; k++){
    short* p = lay_p + (size_t)k*LSTR;
    const float* We1_l = We1 + (size_t)k*257*DH;
    const float* be1_l = be1 + (size_t)k*DH;
    const float* be2_l = be2 + (size_t)k*DH;
    const float* Wx_l  = Wx  + (size_t)k*DH;
    const float* bh_l  = bh  + (size_t)k*DH;

    // node-side hoist of edge-MLP layer 1 (shared by graph & cross calls)
    k_ngemm<1><<<NT/128, 512, 0, stream>>>(h, nullptr, nullptr, nullptr,
                                           p, p + 32768, be1_l, nullptr, Aw, Bw);
    // --- graph edges ---
    k_edge<<<NE/128, 512, 0, stream>>>(permG, esrc, edst, x, Aw, Bw,
                                       p + 65536, We1_l, be2_l, Wx_l, aggm, aggx);
    k_xupd<<<(NT*3+255)/256, 256, 0, stream>>>(x, coords, aggx, dgi);
    k_ngemm<2><<<NT/128, 512, 0, stream>>>(h, aggm, h0, dgi,
                                           p + 98304, nullptr, bh_l, nullptr, c1, nullptr);
    // --- cross edges ---
    k_edge<<<NE/128, 512, 0, stream>>>(permC, csrc, cdst, x, Aw, Bw,
                                       p + 65536, We1_l, be2_l, Wx_l, aggm, aggx);
    k_xupd<<<(NT*3+255)/256, 256, 0, stream>>>(x, coords, aggx, dci);
    k_ngemm<3><<<NT/128, 512, 0, stream>>>(h, aggm, h0, dci,
                                           p + 98304, nullptr, bh_l, c1, h, nullptr);
  }

  k_pool<<<BGR, 512, 0, stream>>>(h, cvalid, pooled);
  k_mlp <<<1, 256, 0, stream>>>(pooled, Wfc, bfc, Wout, bout, (float*)d_out);
}